// Round 9
// baseline (149.188 us; speedup 1.0000x reference)
//
#include <hip/hip_runtime.h>
#include <hip/hip_bf16.h>
#include <math.h>

#define NLVL 4
#define NSLOT 32768
#define SB 512          // score blocks per level (64 rows each)

typedef float f4 __attribute__((ext_vector_type(4)));

// ---------------------------------------------------------------------------
// K_h: h-row dots. grid = (128 rows, 4 levels), 256 threads.
// h = W1 @ x + b1 ; y = h * spec_wr  (irfft(n=1) keeps only the real part)
__global__ __launch_bounds__(256) void k_h(
    const float* __restrict__ s_t, const float* __restrict__ e_t,
    const float* __restrict__ ctx,
    const float* __restrict__ W1_0, const float* __restrict__ b1_0,
    const float* __restrict__ W1_r, const float* __restrict__ b1_r,
    const float* __restrict__ spec_wr, float* __restrict__ ybuf)
{
    const int row = blockIdx.x;
    const int ell = blockIdx.y;
    const int tid = threadIdx.x;
    const int d = (ell == 0) ? 2048 : 2560;
    const float* W1 = (ell == 0) ? W1_0 : (W1_r + (size_t)(ell - 1) * 128 * 2560);
    const float* b1 = (ell == 0) ? b1_0 : (b1_r + (ell - 1) * 128);
    const f4* wrow = (const f4*)(W1 + (size_t)row * d);

    float acc = 0.f;
    if (ell == 0) {
        for (int i4 = tid; i4 < 512; i4 += 256) {
            f4 w = wrow[i4];
            f4 x = (i4 < 256) ? ((const f4*)s_t)[i4]
                              : ((const f4*)e_t)[i4 - 256];
            acc += w.x * x.x + w.y * x.y + w.z * x.z + w.w * x.w;
        }
    } else {
        const f4* c4 = (const f4*)(ctx + (size_t)(ell - 1) * 512);
        for (int i4 = tid; i4 < 640; i4 += 256) {
            f4 w = wrow[i4];
            f4 x;
            if (i4 < 256)      x = ((const f4*)s_t)[i4];
            else if (i4 < 384) x = c4[i4 - 256];
            else               x = ((const f4*)e_t)[i4 - 384];
            acc += w.x * x.x + w.y * x.y + w.z * x.z + w.w * x.w;
        }
    }
    __shared__ float red[256];
    red[tid] = acc;
    __syncthreads();
    for (int off = 128; off > 0; off >>= 1) {
        if (tid < off) red[tid] += red[tid + off];
        __syncthreads();
    }
    if (tid == 0)
        ybuf[ell * 128 + row] = (red[0] + b1[row]) * spec_wr[ell * 128 + row];
}

// ---------------------------------------------------------------------------
// K_zvk: layernorm + gate + v/k projections. grid = (10, 4), 256 threads.
__global__ __launch_bounds__(256) void k_zvk(
    const float* __restrict__ ybuf,
    const float* __restrict__ ln_g, const float* __restrict__ ln_b,
    const float* __restrict__ Wg, const float* __restrict__ bg,
    const float* __restrict__ decay,
    const float* __restrict__ Wv, const float* __restrict__ bv,
    const float* __restrict__ Wk, const float* __restrict__ bk,
    float* __restrict__ vvec, float* __restrict__ kvec,
    float* __restrict__ wgt, float* __restrict__ keepb)
{
    const int ell = blockIdx.y;
    const int t = threadIdx.x;
    __shared__ float red[128];
    __shared__ float sz[128];

    float y = 0.f;
    if (t < 128) { y = ybuf[ell * 128 + t]; red[t] = y; }
    __syncthreads();
    for (int off = 64; off > 0; off >>= 1) {
        if (t < off) red[t] += red[t + off];
        __syncthreads();
    }
    float mu = red[0] * (1.f / 128.f);
    __syncthreads();
    float dd = y - mu;
    if (t < 128) red[t] = dd * dd;
    __syncthreads();
    for (int off = 64; off > 0; off >>= 1) {
        if (t < off) red[t] += red[t + off];
        __syncthreads();
    }
    float rstd = rsqrtf(red[0] * (1.f / 128.f) + 1e-5f);
    __syncthreads();
    if (t < 128) sz[t] = dd * rstd * ln_g[ell * 128 + t] + ln_b[ell * 128 + t];
    __syncthreads();
    if (t < 128) red[t] = Wg[ell * 128 + t] * sz[t];
    __syncthreads();
    for (int off = 64; off > 0; off >>= 1) {
        if (t < off) red[t] += red[t + off];
        __syncthreads();
    }
    if (t == 0 && blockIdx.x == 0) {
        float g = 1.f / (1.f + expf(-(red[0] + bg[ell])));
        wgt[ell] = (g >= 0.1f) ? g : 0.f;
        keepb[ell] = 1.f - decay[ell];
    }

    // v/k projections: 64 rows per block, 4 lanes per row
    const int r = blockIdx.x * 64 + (t >> 2);  // 0..639
    const int lane = t & 3;
    const float* wrow;
    float bias;
    float* outp;
    bool is_v = (r < 512);
    if (is_v) {
        wrow = Wv + ((size_t)ell * 512 + r) * 128;
        bias = bv[ell * 512 + r];
        outp = vvec + ell * 512 + r;
    } else {
        int rk = r - 512;
        wrow = Wk + ((size_t)ell * 128 + rk) * 128;
        bias = bk[ell * 128 + rk];
        outp = kvec + ell * 128 + rk;
    }
    float a = 0.f;
    const f4* w4 = (const f4*)wrow + lane * 8;
    const float* z0 = sz + lane * 32;
    #pragma unroll
    for (int j = 0; j < 8; ++j) {
        f4 w = w4[j];
        a += w.x * z0[j * 4] + w.y * z0[j * 4 + 1] + w.z * z0[j * 4 + 2] + w.w * z0[j * 4 + 3];
    }
    a += __shfl_xor(a, 1);
    a += __shfl_xor(a, 2);
    if (lane == 0) {
        float val = a + bias;
        if (is_v) val = tanhf(val);
        *outp = val;
    }
}

// ---------------------------------------------------------------------------
// K_scores: e = exp(score), per-block partial sums. grid = (SB=512, 4),
// 256 threads, 64 rows/block -> 2048 blocks (32 waves/CU) with 2-row ILP.
__global__ __launch_bounds__(256) void k_scores(
    const float* __restrict__ K_mem, const float* __restrict__ kvec,
    float* __restrict__ expsc, float* __restrict__ partial)
{
    const int ell = blockIdx.y;
    const int tid = threadIdx.x;
    __shared__ float sk[128];
    __shared__ float red[256];
    if (tid < 128) sk[tid] = kvec[ell * 128 + tid];
    __syncthreads();

    const int n0 = blockIdx.x * 64;             // 64 rows per block
    const int gid = tid >> 4, lane = tid & 15;
    const float* z0 = sk + lane * 8;
    const float scale = 0.08838834764831845f;   // 1/sqrt(128)
    float acc = 0.f;
    #pragma unroll
    for (int it = 0; it < 2; ++it) {
        int nA = n0 + it * 32 + gid;
        int nB = nA + 16;
        const f4* ka = (const f4*)K_mem + ((size_t)ell * NSLOT + nA) * 32 + lane * 2;
        const f4* kb = (const f4*)K_mem + ((size_t)ell * NSLOT + nB) * 32 + lane * 2;
        f4 a0 = ka[0], a1 = ka[1];
        f4 b0 = kb[0], b1 = kb[1];
        float a = a0.x * z0[0] + a0.y * z0[1] + a0.z * z0[2] + a0.w * z0[3]
                + a1.x * z0[4] + a1.y * z0[5] + a1.z * z0[6] + a1.w * z0[7];
        float b = b0.x * z0[0] + b0.y * z0[1] + b0.z * z0[2] + b0.w * z0[3]
                + b1.x * z0[4] + b1.y * z0[5] + b1.z * z0[6] + b1.w * z0[7];
        #pragma unroll
        for (int m = 1; m < 16; m <<= 1) { a += __shfl_xor(a, m); b += __shfl_xor(b, m); }
        if (lane == 0) {
            float ea = expf(a * scale);
            float eb = expf(b * scale);
            expsc[(size_t)ell * NSLOT + nA] = ea;
            expsc[(size_t)ell * NSLOT + nB] = eb;
            acc += ea + eb;
        }
    }
    red[tid] = acc;
    __syncthreads();
    for (int off = 128; off > 0; off >>= 1) {
        if (tid < off) red[tid] += red[tid + off];
        __syncthreads();
    }
    if (tid == 0) partial[ell * SB + blockIdx.x] = red[0];
}

// ---------------------------------------------------------------------------
// K_write5: identical to k_write4 EXCEPT regular (cached-path) stores
// instead of nontemporal stores — single-variable A/B vs round 8.
__global__ __launch_bounds__(256) void k_write5(
    const float* __restrict__ M, const float* __restrict__ K_mem,
    const float* __restrict__ expsc, const float* __restrict__ partial,
    const float* __restrict__ wgt, const float* __restrict__ keepb,
    const float* __restrict__ vvec, const float* __restrict__ kvec,
    f4* __restrict__ out)
{
    const int b = blockIdx.x;          // 2048
    const int tid = threadIdx.x;
    const int ell = b >> 9;            // 512 blocks per level
    const int r0 = b << 6;             // 64 rows per block (global row)

    __shared__ float scoef[64];
    __shared__ f4 sv4[128];            // level's v (512 floats)
    __shared__ f4 skv4[32];            // level's k (128 floats)
    __shared__ float red[256];

    if (tid < 128) sv4[tid] = ((const f4*)vvec)[ell * 128 + tid];
    if (tid < 32)  skv4[tid] = ((const f4*)kvec)[ell * 32 + tid];
    red[tid] = partial[ell * SB + tid] + partial[ell * SB + 256 + tid];
    __syncthreads();
    for (int off = 128; off > 0; off >>= 1) {
        if (tid < off) red[tid] += red[tid + off];
        __syncthreads();
    }
    const float scl = wgt[ell] / red[0];
    const float keep = keepb[ell];
    if (tid < 64) scoef[tid] = expsc[r0 + tid] * scl;
    __syncthreads();

    const size_t obase = (size_t)r0 * 160;
    const f4* Mb = (const f4*)M + (size_t)r0 * 128;
    const f4* Kb = (const f4*)K_mem + (size_t)r0 * 32;

    // ---- M phase: 64 rows x 128 f4 = 8192 f4, 4-deep batches ----
    for (int t8 = 0; t8 < 8; ++t8) {
        f4 in[4];
        int idx[4];
        #pragma unroll
        for (int j = 0; j < 4; ++j) {
            idx[j] = t8 * 1024 + j * 256 + tid;
            in[j] = __builtin_nontemporal_load(Mb + idx[j]);
        }
        #pragma unroll
        for (int j = 0; j < 4; ++j) {
            int row = idx[j] >> 7, col = idx[j] & 127;
            float c = scoef[row];
            f4 s = sv4[col];
            f4 o;
            o.x = keep * in[j].x + c * s.x;
            o.y = keep * in[j].y + c * s.y;
            o.z = keep * in[j].z + c * s.z;
            o.w = keep * in[j].w + c * s.w;
            out[obase + (size_t)row * 160 + col] = o;   // regular store
        }
    }

    // ---- K phase: 64 rows x 32 f4 = 2048 f4 ----
    for (int t8 = 0; t8 < 2; ++t8) {
        f4 in[4];
        int idx[4];
        #pragma unroll
        for (int j = 0; j < 4; ++j) {
            idx[j] = t8 * 1024 + j * 256 + tid;
            in[j] = Kb[idx[j]];                     // cached: L3-hot from k_scores
        }
        #pragma unroll
        for (int j = 0; j < 4; ++j) {
            int row = idx[j] >> 5, col = idx[j] & 31;
            float c = scoef[row];
            f4 s = skv4[col];
            f4 o;
            o.x = keep * in[j].x + c * s.x;
            o.y = keep * in[j].y + c * s.y;
            o.z = keep * in[j].z + c * s.z;
            o.w = keep * in[j].w + c * s.w;
            out[obase + (size_t)row * 160 + 128 + col] = o;   // regular store
        }
    }
}

extern "C" void kernel_launch(void* const* d_in, const int* in_sizes, int n_in,
                              void* d_out, int out_size, void* d_ws, size_t ws_size,
                              hipStream_t stream) {
    const float* s_t    = (const float*)d_in[0];
    const float* e_t    = (const float*)d_in[1];
    const float* ctx    = (const float*)d_in[2];
    const float* M      = (const float*)d_in[3];
    const float* K_mem  = (const float*)d_in[4];
    const float* decay  = (const float*)d_in[5];
    const float* W1_0   = (const float*)d_in[6];
    const float* b1_0   = (const float*)d_in[7];
    const float* W1_r   = (const float*)d_in[8];
    const float* b1_r   = (const float*)d_in[9];
    const float* spec_wr= (const float*)d_in[10];
    // d_in[11] = spec_wi: unused — irfft(n=1) keeps only the real part
    const float* ln_g   = (const float*)d_in[12];
    const float* ln_b   = (const float*)d_in[13];
    const float* Wg     = (const float*)d_in[14];
    const float* bg     = (const float*)d_in[15];
    const float* Wv     = (const float*)d_in[16];
    const float* bv     = (const float*)d_in[17];
    const float* Wk     = (const float*)d_in[18];
    const float* bk     = (const float*)d_in[19];

    float* ws = (float*)d_ws;
    float* expsc   = ws;                 // L*N            = 131072
    float* partial = ws + 131072;        // L*SB           = 2048
    float* ybuf    = ws + 133120;        // 512
    float* kvec    = ws + 133632;        // 512
    float* vvec    = ws + 134144;        // 2048
    float* wgt     = ws + 136192;        // 4
    float* keepb   = ws + 136196;        // 4

    dim3 gh(128, NLVL);
    k_h<<<gh, 256, 0, stream>>>(s_t, e_t, ctx, W1_0, b1_0, W1_r, b1_r,
                                spec_wr, ybuf);

    dim3 gzvk(10, NLVL);
    k_zvk<<<gzvk, 256, 0, stream>>>(ybuf, ln_g, ln_b, Wg, bg, decay,
                                    Wv, bv, Wk, bk, vvec, kvec, wgt, keepb);

    dim3 gs(SB, NLVL);
    k_scores<<<gs, 256, 0, stream>>>(K_mem, kvec, expsc, partial);

    k_write5<<<2048, 256, 0, stream>>>(M, K_mem, expsc, partial, wgt, keepb,
                                       vvec, kvec, (f4*)d_out);
}

// Round 10
// 143.098 us; speedup vs baseline: 1.0426x; 1.0426x over previous
//
#include <hip/hip_runtime.h>
#include <hip/hip_bf16.h>
#include <math.h>

#define NLVL 4
#define NSLOT 32768
#define SB 512          // score blocks per level (64 rows each)

typedef float f4 __attribute__((ext_vector_type(4)));

// ---------------------------------------------------------------------------
// K_h: h-row dots. grid = (128 rows, 4 levels), 256 threads.
// h = W1 @ x + b1 ; y = h * spec_wr  (irfft(n=1) keeps only the real part)
__global__ __launch_bounds__(256) void k_h(
    const float* __restrict__ s_t, const float* __restrict__ e_t,
    const float* __restrict__ ctx,
    const float* __restrict__ W1_0, const float* __restrict__ b1_0,
    const float* __restrict__ W1_r, const float* __restrict__ b1_r,
    const float* __restrict__ spec_wr, float* __restrict__ ybuf)
{
    const int row = blockIdx.x;
    const int ell = blockIdx.y;
    const int tid = threadIdx.x;
    const int d = (ell == 0) ? 2048 : 2560;
    const float* W1 = (ell == 0) ? W1_0 : (W1_r + (size_t)(ell - 1) * 128 * 2560);
    const float* b1 = (ell == 0) ? b1_0 : (b1_r + (ell - 1) * 128);
    const f4* wrow = (const f4*)(W1 + (size_t)row * d);

    float acc = 0.f;
    if (ell == 0) {
        for (int i4 = tid; i4 < 512; i4 += 256) {
            f4 w = wrow[i4];
            f4 x = (i4 < 256) ? ((const f4*)s_t)[i4]
                              : ((const f4*)e_t)[i4 - 256];
            acc += w.x * x.x + w.y * x.y + w.z * x.z + w.w * x.w;
        }
    } else {
        const f4* c4 = (const f4*)(ctx + (size_t)(ell - 1) * 512);
        for (int i4 = tid; i4 < 640; i4 += 256) {
            f4 w = wrow[i4];
            f4 x;
            if (i4 < 256)      x = ((const f4*)s_t)[i4];
            else if (i4 < 384) x = c4[i4 - 256];
            else               x = ((const f4*)e_t)[i4 - 384];
            acc += w.x * x.x + w.y * x.y + w.z * x.z + w.w * x.w;
        }
    }
    __shared__ float red[256];
    red[tid] = acc;
    __syncthreads();
    for (int off = 128; off > 0; off >>= 1) {
        if (tid < off) red[tid] += red[tid + off];
        __syncthreads();
    }
    if (tid == 0)
        ybuf[ell * 128 + row] = (red[0] + b1[row]) * spec_wr[ell * 128 + row];
}

// ---------------------------------------------------------------------------
// K_zvk: layernorm + gate + v/k projections. grid = (10, 4), 256 threads.
__global__ __launch_bounds__(256) void k_zvk(
    const float* __restrict__ ybuf,
    const float* __restrict__ ln_g, const float* __restrict__ ln_b,
    const float* __restrict__ Wg, const float* __restrict__ bg,
    const float* __restrict__ decay,
    const float* __restrict__ Wv, const float* __restrict__ bv,
    const float* __restrict__ Wk, const float* __restrict__ bk,
    float* __restrict__ vvec, float* __restrict__ kvec,
    float* __restrict__ wgt, float* __restrict__ keepb)
{
    const int ell = blockIdx.y;
    const int t = threadIdx.x;
    __shared__ float red[128];
    __shared__ float sz[128];

    float y = 0.f;
    if (t < 128) { y = ybuf[ell * 128 + t]; red[t] = y; }
    __syncthreads();
    for (int off = 64; off > 0; off >>= 1) {
        if (t < off) red[t] += red[t + off];
        __syncthreads();
    }
    float mu = red[0] * (1.f / 128.f);
    __syncthreads();
    float dd = y - mu;
    if (t < 128) red[t] = dd * dd;
    __syncthreads();
    for (int off = 64; off > 0; off >>= 1) {
        if (t < off) red[t] += red[t + off];
        __syncthreads();
    }
    float rstd = rsqrtf(red[0] * (1.f / 128.f) + 1e-5f);
    __syncthreads();
    if (t < 128) sz[t] = dd * rstd * ln_g[ell * 128 + t] + ln_b[ell * 128 + t];
    __syncthreads();
    if (t < 128) red[t] = Wg[ell * 128 + t] * sz[t];
    __syncthreads();
    for (int off = 64; off > 0; off >>= 1) {
        if (t < off) red[t] += red[t + off];
        __syncthreads();
    }
    if (t == 0 && blockIdx.x == 0) {
        float g = 1.f / (1.f + expf(-(red[0] + bg[ell])));
        wgt[ell] = (g >= 0.1f) ? g : 0.f;
        keepb[ell] = 1.f - decay[ell];
    }

    // v/k projections: 64 rows per block, 4 lanes per row
    const int r = blockIdx.x * 64 + (t >> 2);  // 0..639
    const int lane = t & 3;
    const float* wrow;
    float bias;
    float* outp;
    bool is_v = (r < 512);
    if (is_v) {
        wrow = Wv + ((size_t)ell * 512 + r) * 128;
        bias = bv[ell * 512 + r];
        outp = vvec + ell * 512 + r;
    } else {
        int rk = r - 512;
        wrow = Wk + ((size_t)ell * 128 + rk) * 128;
        bias = bk[ell * 128 + rk];
        outp = kvec + ell * 128 + rk;
    }
    float a = 0.f;
    const f4* w4 = (const f4*)wrow + lane * 8;
    const float* z0 = sz + lane * 32;
    #pragma unroll
    for (int j = 0; j < 8; ++j) {
        f4 w = w4[j];
        a += w.x * z0[j * 4] + w.y * z0[j * 4 + 1] + w.z * z0[j * 4 + 2] + w.w * z0[j * 4 + 3];
    }
    a += __shfl_xor(a, 1);
    a += __shfl_xor(a, 2);
    if (lane == 0) {
        float val = a + bias;
        if (is_v) val = tanhf(val);
        *outp = val;
    }
}

// ---------------------------------------------------------------------------
// K_scores: e = exp(score), per-block partial sums. grid = (SB=512, 4),
// 256 threads, 64 rows/block -> 2048 blocks (32 waves/CU) with 2-row ILP.
__global__ __launch_bounds__(256) void k_scores(
    const float* __restrict__ K_mem, const float* __restrict__ kvec,
    float* __restrict__ expsc, float* __restrict__ partial)
{
    const int ell = blockIdx.y;
    const int tid = threadIdx.x;
    __shared__ float sk[128];
    __shared__ float red[256];
    if (tid < 128) sk[tid] = kvec[ell * 128 + tid];
    __syncthreads();

    const int n0 = blockIdx.x * 64;             // 64 rows per block
    const int gid = tid >> 4, lane = tid & 15;
    const float* z0 = sk + lane * 8;
    const float scale = 0.08838834764831845f;   // 1/sqrt(128)
    float acc = 0.f;
    #pragma unroll
    for (int it = 0; it < 2; ++it) {
        int nA = n0 + it * 32 + gid;
        int nB = nA + 16;
        const f4* ka = (const f4*)K_mem + ((size_t)ell * NSLOT + nA) * 32 + lane * 2;
        const f4* kb = (const f4*)K_mem + ((size_t)ell * NSLOT + nB) * 32 + lane * 2;
        f4 a0 = ka[0], a1 = ka[1];
        f4 b0 = kb[0], b1 = kb[1];
        float a = a0.x * z0[0] + a0.y * z0[1] + a0.z * z0[2] + a0.w * z0[3]
                + a1.x * z0[4] + a1.y * z0[5] + a1.z * z0[6] + a1.w * z0[7];
        float b = b0.x * z0[0] + b0.y * z0[1] + b0.z * z0[2] + b0.w * z0[3]
                + b1.x * z0[4] + b1.y * z0[5] + b1.z * z0[6] + b1.w * z0[7];
        #pragma unroll
        for (int m = 1; m < 16; m <<= 1) { a += __shfl_xor(a, m); b += __shfl_xor(b, m); }
        if (lane == 0) {
            float ea = expf(a * scale);
            float eb = expf(b * scale);
            expsc[(size_t)ell * NSLOT + nA] = ea;
            expsc[(size_t)ell * NSLOT + nB] = eb;
            acc += ea + eb;
        }
    }
    red[tid] = acc;
    __syncthreads();
    for (int off = 128; off > 0; off >>= 1) {
        if (tid < off) red[tid] += red[tid + off];
        __syncthreads();
    }
    if (tid == 0) partial[ell * SB + blockIdx.x] = red[0];
}

// ---------------------------------------------------------------------------
// K_write4: block owns 64 contiguous rows (2048 blocks x 256 threads).
// Phase-split (M-half then K-half): every wave uniform, branch-free,
// shift addressing, 4-deep load batches. nt loads on M, nt stores on out.
// (nt stores measured 6 us faster than cached stores — round 8 vs 9 A/B.)
__global__ __launch_bounds__(256) void k_write4(
    const float* __restrict__ M, const float* __restrict__ K_mem,
    const float* __restrict__ expsc, const float* __restrict__ partial,
    const float* __restrict__ wgt, const float* __restrict__ keepb,
    const float* __restrict__ vvec, const float* __restrict__ kvec,
    f4* __restrict__ out)
{
    const int b = blockIdx.x;          // 2048
    const int tid = threadIdx.x;
    const int ell = b >> 9;            // 512 blocks per level
    const int r0 = b << 6;             // 64 rows per block (global row)

    __shared__ float scoef[64];
    __shared__ f4 sv4[128];            // level's v (512 floats)
    __shared__ f4 skv4[32];            // level's k (128 floats)
    __shared__ float red[256];

    if (tid < 128) sv4[tid] = ((const f4*)vvec)[ell * 128 + tid];
    if (tid < 32)  skv4[tid] = ((const f4*)kvec)[ell * 32 + tid];
    red[tid] = partial[ell * SB + tid] + partial[ell * SB + 256 + tid];
    __syncthreads();
    for (int off = 128; off > 0; off >>= 1) {
        if (tid < off) red[tid] += red[tid + off];
        __syncthreads();
    }
    const float scl = wgt[ell] / red[0];
    const float keep = keepb[ell];
    if (tid < 64) scoef[tid] = expsc[r0 + tid] * scl;
    __syncthreads();

    const size_t obase = (size_t)r0 * 160;
    const f4* Mb = (const f4*)M + (size_t)r0 * 128;
    const f4* Kb = (const f4*)K_mem + (size_t)r0 * 32;

    // ---- M phase: 64 rows x 128 f4 = 8192 f4, 4-deep batches ----
    for (int t8 = 0; t8 < 8; ++t8) {
        f4 in[4];
        int idx[4];
        #pragma unroll
        for (int j = 0; j < 4; ++j) {
            idx[j] = t8 * 1024 + j * 256 + tid;
            in[j] = __builtin_nontemporal_load(Mb + idx[j]);
        }
        #pragma unroll
        for (int j = 0; j < 4; ++j) {
            int row = idx[j] >> 7, col = idx[j] & 127;
            float c = scoef[row];
            f4 s = sv4[col];
            f4 o;
            o.x = keep * in[j].x + c * s.x;
            o.y = keep * in[j].y + c * s.y;
            o.z = keep * in[j].z + c * s.z;
            o.w = keep * in[j].w + c * s.w;
            __builtin_nontemporal_store(o, out + obase + (size_t)row * 160 + col);
        }
    }

    // ---- K phase: 64 rows x 32 f4 = 2048 f4 ----
    for (int t8 = 0; t8 < 2; ++t8) {
        f4 in[4];
        int idx[4];
        #pragma unroll
        for (int j = 0; j < 4; ++j) {
            idx[j] = t8 * 1024 + j * 256 + tid;
            in[j] = Kb[idx[j]];                     // cached: L3-hot from k_scores
        }
        #pragma unroll
        for (int j = 0; j < 4; ++j) {
            int row = idx[j] >> 5, col = idx[j] & 31;
            float c = scoef[row];
            f4 s = skv4[col];
            f4 o;
            o.x = keep * in[j].x + c * s.x;
            o.y = keep * in[j].y + c * s.y;
            o.z = keep * in[j].z + c * s.z;
            o.w = keep * in[j].w + c * s.w;
            __builtin_nontemporal_store(o, out + obase + (size_t)row * 160 + 128 + col);
        }
    }
}

extern "C" void kernel_launch(void* const* d_in, const int* in_sizes, int n_in,
                              void* d_out, int out_size, void* d_ws, size_t ws_size,
                              hipStream_t stream) {
    const float* s_t    = (const float*)d_in[0];
    const float* e_t    = (const float*)d_in[1];
    const float* ctx    = (const float*)d_in[2];
    const float* M      = (const float*)d_in[3];
    const float* K_mem  = (const float*)d_in[4];
    const float* decay  = (const float*)d_in[5];
    const float* W1_0   = (const float*)d_in[6];
    const float* b1_0   = (const float*)d_in[7];
    const float* W1_r   = (const float*)d_in[8];
    const float* b1_r   = (const float*)d_in[9];
    const float* spec_wr= (const float*)d_in[10];
    // d_in[11] = spec_wi: unused — irfft(n=1) keeps only the real part
    const float* ln_g   = (const float*)d_in[12];
    const float* ln_b   = (const float*)d_in[13];
    const float* Wg     = (const float*)d_in[14];
    const float* bg     = (const float*)d_in[15];
    const float* Wv     = (const float*)d_in[16];
    const float* bv     = (const float*)d_in[17];
    const float* Wk     = (const float*)d_in[18];
    const float* bk     = (const float*)d_in[19];

    float* ws = (float*)d_ws;
    float* expsc   = ws;                 // L*N            = 131072
    float* partial = ws + 131072;        // L*SB           = 2048
    float* ybuf    = ws + 133120;        // 512
    float* kvec    = ws + 133632;        // 512
    float* vvec    = ws + 134144;        // 2048
    float* wgt     = ws + 136192;        // 4
    float* keepb   = ws + 136196;        // 4

    dim3 gh(128, NLVL);
    k_h<<<gh, 256, 0, stream>>>(s_t, e_t, ctx, W1_0, b1_0, W1_r, b1_r,
                                spec_wr, ybuf);

    dim3 gzvk(10, NLVL);
    k_zvk<<<gzvk, 256, 0, stream>>>(ybuf, ln_g, ln_b, Wg, bg, decay,
                                    Wv, bv, Wk, bk, vvec, kvec, wgt, keepb);

    dim3 gs(SB, NLVL);
    k_scores<<<gs, 256, 0, stream>>>(K_mem, kvec, expsc, partial);

    k_write4<<<2048, 256, 0, stream>>>(M, K_mem, expsc, partial, wgt, keepb,
                                       vvec, kvec, (f4*)d_out);
}